// Round 1
// baseline (252.880 us; speedup 1.0000x reference)
//
#include <hip/hip_runtime.h>
#include <stdint.h>

#define WS_TOK 49
#define DIMC 128

typedef float  f32x4   __attribute__((ext_vector_type(4)));
typedef float  float4v __attribute__((ext_vector_type(4)));
typedef short  short4v __attribute__((ext_vector_type(4)));
typedef short  short8v __attribute__((ext_vector_type(8)));
typedef __bf16 bf16x8  __attribute__((ext_vector_type(8)));

static __device__ __forceinline__ short f2bf(float f) {
  unsigned u = __builtin_bit_cast(unsigned, f);
  u += 0x7FFFu + ((u >> 16) & 1u);
  return (short)(u >> 16);
}

static __device__ __forceinline__ f32x4 mfma16(short8v a, short8v b, f32x4 c) {
  return __builtin_amdgcn_mfma_f32_16x16x32_bf16(
      __builtin_bit_cast(bf16x8, a), __builtin_bit_cast(bf16x8, b), c, 0, 0, 0);
}

// Prelude: convert qkv_w (384x128) and proj_w (128x128) f32 -> bf16 into workspace.
__global__ void cvt_weights_kernel(const float* __restrict__ qkv_w,
                                   const float* __restrict__ proj_w,
                                   short* __restrict__ wq, short* __restrict__ wp) {
  int i = blockIdx.x * 256 + threadIdx.x;   // grid sized to exactly 49152
  wq[i] = f2bf(qkv_w[i]);
  if (i < 16384) wp[i] = f2bf(proj_w[i]);
}

// One block = one window (49 tokens padded to 64). 512 threads = 8 waves.
// wave (g,h): g = query/token half (32 rows), h = head.
__global__ __launch_bounds__(512)
void win_attn_kernel(const float* __restrict__ x,
                     const float* __restrict__ mask,
                     const float* __restrict__ qkv_b,
                     const float* __restrict__ proj_b,
                     const float* __restrict__ bias_table,
                     const short* __restrict__ wq,
                     const short* __restrict__ wp,
                     float* __restrict__ out) {
  __shared__ __align__(16) short smem[65536];        // 128 KiB
  short* xb  = smem;            // [64][136] bf16 x tile (rows >=49 zeroed)
  short* qsm = smem + 8704;     // [4][64][40] q (scaled)
  short* ksm = smem + 18944;    // [4][64][40] k
  short* vtm = smem + 29184;    // [4][32][72] v transposed: [d][token]
  short* psm = smem + 38400;    // [4][64][72] P transposed: [query][key]
  short* aom = smem + 56832;    // [64][136] attention output (token x feature)

  const int b    = blockIdx.x;
  const int tid  = threadIdx.x;
  const int lane = tid & 63;
  const int wv   = tid >> 6;
  const int h    = wv & 3;
  const int g    = wv >> 2;
  const int l15  = lane & 15;
  const int lhi  = lane >> 4;

  // ---- Phase 0: stage x -> bf16 LDS, zero pad rows 49..63
  {
    short4v z = {0, 0, 0, 0};
    for (int idx = tid; idx < 510; idx += 512)
      *(short4v*)&xb[49 * 136 + idx * 4] = z;
    const float* xw = x + (long)b * (WS_TOK * DIMC);
    for (int idx = tid; idx < 1568; idx += 512) {
      int m  = idx >> 5;
      int c0 = (idx & 31) << 2;
      float4v v = *(const float4v*)&xw[m * DIMC + c0];
      short4v s;
      s[0] = f2bf(v[0]); s[1] = f2bf(v[1]); s[2] = f2bf(v[2]); s[3] = f2bf(v[3]);
      *(short4v*)&xb[m * 136 + c0] = s;
    }
  }
  __syncthreads();

  // ---- Phase 1: QKV projection (this wave: rows g*32..+32, cols of head h)
  {
    short8v afr[2][4];
#pragma unroll
    for (int mt = 0; mt < 2; ++mt)
#pragma unroll
      for (int ks = 0; ks < 4; ++ks)
        afr[mt][ks] = *(const short8v*)&xb[(g * 32 + mt * 16 + l15) * 136 + ks * 32 + lhi * 8];

    const float scale = 0.1767766952966369f;  // 32^-0.5
#pragma unroll
    for (int mat = 0; mat < 3; ++mat) {
#pragma unroll
      for (int nt = 0; nt < 2; ++nt) {
        const int ncol = mat * 128 + h * 32 + nt * 16 + l15;
        short8v bfr[4];
#pragma unroll
        for (int ks = 0; ks < 4; ++ks)
          bfr[ks] = *(const short8v*)&wq[ncol * 128 + ks * 32 + lhi * 8];
        const float bias = qkv_b[ncol];
        f32x4 a0 = {bias, bias, bias, bias};
        f32x4 a1 = a0;
#pragma unroll
        for (int ks = 0; ks < 4; ++ks) {
          a0 = mfma16(afr[0][ks], bfr[ks], a0);
          a1 = mfma16(afr[1][ks], bfr[ks], a1);
        }
        const int d = nt * 16 + l15;
        if (mat == 0) {
#pragma unroll
          for (int r = 0; r < 4; ++r) {
            qsm[h * 2560 + (g * 32 + lhi * 4 + r) * 40 + d]      = f2bf(a0[r] * scale);
            qsm[h * 2560 + (g * 32 + 16 + lhi * 4 + r) * 40 + d] = f2bf(a1[r] * scale);
          }
        } else if (mat == 1) {
#pragma unroll
          for (int r = 0; r < 4; ++r) {
            ksm[h * 2560 + (g * 32 + lhi * 4 + r) * 40 + d]      = f2bf(a0[r]);
            ksm[h * 2560 + (g * 32 + 16 + lhi * 4 + r) * 40 + d] = f2bf(a1[r]);
          }
        } else {
          short4v p0, p1;
#pragma unroll
          for (int r = 0; r < 4; ++r) { p0[r] = f2bf(a0[r]); p1[r] = f2bf(a1[r]); }
          *(short4v*)&vtm[h * 2304 + d * 72 + g * 32 + lhi * 4]      = p0;
          *(short4v*)&vtm[h * 2304 + d * 72 + g * 32 + 16 + lhi * 4] = p1;
        }
      }
    }
  }
  __syncthreads();

  // ---- Phase 2: attention (head h, queries g*32..+32), swapped S = K*Q^T
  {
    short8v kfr[4], qfr[2];
#pragma unroll
    for (int i = 0; i < 4; ++i)
      kfr[i] = *(const short8v*)&ksm[h * 2560 + (i * 16 + l15) * 40 + lhi * 8];
#pragma unroll
    for (int j = 0; j < 2; ++j)
      qfr[j] = *(const short8v*)&qsm[h * 2560 + (g * 32 + j * 16 + l15) * 40 + lhi * 8];

    const float* maskw = mask + (b & 63) * (49 * 49);

#pragma unroll
    for (int j = 0; j < 2; ++j) {
      const f32x4 zero = {0.f, 0.f, 0.f, 0.f};
      f32x4 s[4];
#pragma unroll
      for (int i = 0; i < 4; ++i) s[i] = mfma16(kfr[i], qfr[j], zero);

      const int qq = g * 32 + j * 16 + l15;      // query column held by this lane
      const unsigned qi = (unsigned)qq / 7u;
      const unsigned qjj = (unsigned)qq - qi * 7u;
      float lg[4][4];
#pragma unroll
      for (int i = 0; i < 4; ++i) {
#pragma unroll
        for (int r = 0; r < 4; ++r) {
          const int key = i * 16 + lhi * 4 + r;
          float v = s[i][r];
          if (qq < 49 && key < 49) {
            const unsigned ki = (unsigned)key / 7u;
            const unsigned kj = (unsigned)key - ki * 7u;
            const int idx = (int)((qi - ki + 6u) * 13u + (qjj - kj + 6u));
            v += bias_table[idx * 4 + h] + maskw[qq * 49 + key];
          }
          if (key >= 49) v = -1e30f;
          lg[i][r] = v;
        }
      }
      float mx = lg[0][0];
#pragma unroll
      for (int i = 0; i < 4; ++i)
#pragma unroll
        for (int r = 0; r < 4; ++r) mx = fmaxf(mx, lg[i][r]);
      mx = fmaxf(mx, __shfl_xor(mx, 16));
      mx = fmaxf(mx, __shfl_xor(mx, 32));
      float sum = 0.f;
#pragma unroll
      for (int i = 0; i < 4; ++i)
#pragma unroll
        for (int r = 0; r < 4; ++r) { lg[i][r] = __expf(lg[i][r] - mx); sum += lg[i][r]; }
      sum += __shfl_xor(sum, 16);
      sum += __shfl_xor(sum, 32);
      const float inv = 1.f / sum;
#pragma unroll
      for (int i = 0; i < 4; ++i) {
        short4v p;
#pragma unroll
        for (int r = 0; r < 4; ++r) p[r] = f2bf(lg[i][r] * inv);
        *(short4v*)&psm[h * 4608 + qq * 72 + i * 16 + lhi * 4] = p;
      }
    }

    // ---- PV: out[q][d] = sum_k P[q][k] * V[k][d]
    f32x4 oacc[2][2];
    const f32x4 zero = {0.f, 0.f, 0.f, 0.f};
#pragma unroll
    for (int mt = 0; mt < 2; ++mt)
#pragma unroll
      for (int nt = 0; nt < 2; ++nt) oacc[mt][nt] = zero;
#pragma unroll
    for (int ks = 0; ks < 2; ++ks) {
      short8v pf[2], vf[2];
#pragma unroll
      for (int mt = 0; mt < 2; ++mt)
        pf[mt] = *(const short8v*)&psm[h * 4608 + (g * 32 + mt * 16 + l15) * 72 + ks * 32 + lhi * 8];
#pragma unroll
      for (int nt = 0; nt < 2; ++nt)
        vf[nt] = *(const short8v*)&vtm[h * 2304 + (nt * 16 + l15) * 72 + ks * 32 + lhi * 8];
#pragma unroll
      for (int mt = 0; mt < 2; ++mt)
#pragma unroll
        for (int nt = 0; nt < 2; ++nt) oacc[mt][nt] = mfma16(pf[mt], vf[nt], oacc[mt][nt]);
    }
#pragma unroll
    for (int mt = 0; mt < 2; ++mt)
#pragma unroll
      for (int nt = 0; nt < 2; ++nt)
#pragma unroll
        for (int r = 0; r < 4; ++r)
          aom[(g * 32 + mt * 16 + lhi * 4 + r) * 136 + h * 32 + nt * 16 + l15] =
              f2bf(oacc[mt][nt][r]);
  }
  __syncthreads();

  // ---- Phase 3: output projection Y = AO @ proj_w^T + proj_b
  {
    short8v afr[2][4];
#pragma unroll
    for (int mt = 0; mt < 2; ++mt)
#pragma unroll
      for (int ks = 0; ks < 4; ++ks)
        afr[mt][ks] = *(const short8v*)&aom[(g * 32 + mt * 16 + l15) * 136 + ks * 32 + lhi * 8];

    float* outw = out + (long)b * (WS_TOK * DIMC);
#pragma unroll
    for (int nt = 0; nt < 2; ++nt) {
      const int ncol = h * 32 + nt * 16 + l15;
      short8v wfr[4];
#pragma unroll
      for (int ks = 0; ks < 4; ++ks)
        wfr[ks] = *(const short8v*)&wp[ncol * 128 + ks * 32 + lhi * 8];
      const float pb = proj_b[ncol];
      f32x4 a0 = {pb, pb, pb, pb};
      f32x4 a1 = a0;
#pragma unroll
      for (int ks = 0; ks < 4; ++ks) {
        a0 = mfma16(afr[0][ks], wfr[ks], a0);
        a1 = mfma16(afr[1][ks], wfr[ks], a1);
      }
#pragma unroll
      for (int r = 0; r < 4; ++r) {
        const int m0 = g * 32 + lhi * 4 + r;
        if (m0 < 49) outw[m0 * 128 + ncol] = a0[r];
        const int m1 = m0 + 16;
        if (m1 < 49) outw[m1 * 128 + ncol] = a1[r];
      }
    }
  }
}

extern "C" void kernel_launch(void* const* d_in, const int* in_sizes, int n_in,
                              void* d_out, int out_size, void* d_ws, size_t ws_size,
                              hipStream_t stream) {
  const float* x          = (const float*)d_in[0];
  const float* mask       = (const float*)d_in[1];
  const float* qkv_w      = (const float*)d_in[2];
  const float* qkv_b      = (const float*)d_in[3];
  const float* proj_w     = (const float*)d_in[4];
  const float* proj_b     = (const float*)d_in[5];
  const float* bias_table = (const float*)d_in[6];

  short* wq = (short*)d_ws;        // 384*128 bf16
  short* wp = wq + 49152;          // 128*128 bf16

  cvt_weights_kernel<<<dim3(192), dim3(256), 0, stream>>>(qkv_w, proj_w, wq, wp);
  win_attn_kernel<<<dim3(4096), dim3(512), 0, stream>>>(
      x, mask, qkv_b, proj_b, bias_table, wq, wp, (float*)d_out);
}

// Round 2
// 211.111 us; speedup vs baseline: 1.1979x; 1.1979x over previous
//
#include <hip/hip_runtime.h>
#include <stdint.h>

#define WS_TOK 49
#define DIMC 128

typedef float  f32x4   __attribute__((ext_vector_type(4)));
typedef float  float4v __attribute__((ext_vector_type(4)));
typedef short  short4v __attribute__((ext_vector_type(4)));
typedef short  short8v __attribute__((ext_vector_type(8)));
typedef __bf16 bf16x8  __attribute__((ext_vector_type(8)));

static __device__ __forceinline__ short f2bf(float f) {
  unsigned u = __builtin_bit_cast(unsigned, f);
  u += 0x7FFFu + ((u >> 16) & 1u);
  return (short)(u >> 16);
}

static __device__ __forceinline__ f32x4 mfma16(short8v a, short8v b, f32x4 c) {
  return __builtin_amdgcn_mfma_f32_16x16x32_bf16(
      __builtin_bit_cast(bf16x8, a), __builtin_bit_cast(bf16x8, b), c, 0, 0, 0);
}

// Prelude: convert qkv_w (384x128) and proj_w (128x128) f32 -> bf16 into workspace.
__global__ void cvt_weights_kernel(const float* __restrict__ qkv_w,
                                   const float* __restrict__ proj_w,
                                   short* __restrict__ wq, short* __restrict__ wp) {
  int i = blockIdx.x * 256 + threadIdx.x;   // grid sized to exactly 49152
  wq[i] = f2bf(qkv_w[i]);
  if (i < 16384) wp[i] = f2bf(proj_w[i]);
}

// One block = one window (49 tokens padded to 64). 512 threads = 8 waves.
// wave (g,h): g = query/token half (32 rows), h = head.
// LDS aliasing (75 KiB total -> 2 blocks/CU):
//   [0,8704)      xb  [64][136]  -> later aom [64][136]
//   [8704,18944)  qsm [4][64][40]-+-> later psm [4][64][72] (spans q+k)
//   [18944,29184) ksm [4][64][40]-+
//   [29184,38400) vtm [4][32][72]
__global__ __launch_bounds__(512, 4)
void win_attn_kernel(const float* __restrict__ x,
                     const float* __restrict__ mask,
                     const float* __restrict__ qkv_b,
                     const float* __restrict__ proj_b,
                     const float* __restrict__ bias_table,
                     const short* __restrict__ wq,
                     const short* __restrict__ wp,
                     float* __restrict__ out) {
  __shared__ __align__(16) short smem[38400];        // 75 KiB
  short* xb  = smem;            // [64][136] bf16 x tile (rows >=49 zeroed)
  short* qsm = smem + 8704;     // [4][64][40] q (scaled)
  short* ksm = smem + 18944;    // [4][64][40] k
  short* vtm = smem + 29184;    // [4][32][72] v transposed: [d][token]
  short* psm = smem + 8704;     // ALIAS over q+k: [4][64][72] P transposed
  short* aom = smem;            // ALIAS over xb: [64][136] attention output

  const int b    = blockIdx.x;
  const int tid  = threadIdx.x;
  const int lane = tid & 63;
  const int wv   = tid >> 6;
  const int h    = wv & 3;
  const int g    = wv >> 2;
  const int l15  = lane & 15;
  const int lhi  = lane >> 4;

  // ---- Phase 0: stage x -> bf16 LDS, zero pad rows 49..63
  {
    short4v z = {0, 0, 0, 0};
    for (int idx = tid; idx < 510; idx += 512)
      *(short4v*)&xb[49 * 136 + idx * 4] = z;
    const float* xw = x + (long)b * (WS_TOK * DIMC);
    for (int idx = tid; idx < 1568; idx += 512) {
      int m  = idx >> 5;
      int c0 = (idx & 31) << 2;
      float4v v = *(const float4v*)&xw[m * DIMC + c0];
      short4v s;
      s[0] = f2bf(v[0]); s[1] = f2bf(v[1]); s[2] = f2bf(v[2]); s[3] = f2bf(v[3]);
      *(short4v*)&xb[m * 136 + c0] = s;
    }
  }
  __syncthreads();

  // ---- Phase 1: QKV projection (this wave: rows g*32..+32, cols of head h)
  {
    short8v afr[2][4];
#pragma unroll
    for (int mt = 0; mt < 2; ++mt)
#pragma unroll
      for (int ks = 0; ks < 4; ++ks)
        afr[mt][ks] = *(const short8v*)&xb[(g * 32 + mt * 16 + l15) * 136 + ks * 32 + lhi * 8];

    const float scale = 0.1767766952966369f;  // 32^-0.5
#pragma unroll
    for (int mat = 0; mat < 3; ++mat) {
#pragma unroll
      for (int nt = 0; nt < 2; ++nt) {
        const int ncol = mat * 128 + h * 32 + nt * 16 + l15;
        short8v bfr[4];
#pragma unroll
        for (int ks = 0; ks < 4; ++ks)
          bfr[ks] = *(const short8v*)&wq[ncol * 128 + ks * 32 + lhi * 8];
        const float bias = qkv_b[ncol];
        f32x4 a0 = {bias, bias, bias, bias};
        f32x4 a1 = a0;
#pragma unroll
        for (int ks = 0; ks < 4; ++ks) {
          a0 = mfma16(afr[0][ks], bfr[ks], a0);
          a1 = mfma16(afr[1][ks], bfr[ks], a1);
        }
        const int d = nt * 16 + l15;
        if (mat == 0) {
#pragma unroll
          for (int r = 0; r < 4; ++r) {
            qsm[h * 2560 + (g * 32 + lhi * 4 + r) * 40 + d]      = f2bf(a0[r] * scale);
            qsm[h * 2560 + (g * 32 + 16 + lhi * 4 + r) * 40 + d] = f2bf(a1[r] * scale);
          }
        } else if (mat == 1) {
#pragma unroll
          for (int r = 0; r < 4; ++r) {
            ksm[h * 2560 + (g * 32 + lhi * 4 + r) * 40 + d]      = f2bf(a0[r]);
            ksm[h * 2560 + (g * 32 + 16 + lhi * 4 + r) * 40 + d] = f2bf(a1[r]);
          }
        } else {
          short4v p0, p1;
#pragma unroll
          for (int r = 0; r < 4; ++r) { p0[r] = f2bf(a0[r]); p1[r] = f2bf(a1[r]); }
          *(short4v*)&vtm[h * 2304 + d * 72 + g * 32 + lhi * 4]      = p0;
          *(short4v*)&vtm[h * 2304 + d * 72 + g * 32 + 16 + lhi * 4] = p1;
        }
      }
    }
  }
  __syncthreads();

  // ---- Phase 2: attention (head h, queries g*32..+32), swapped S = K*Q^T
  {
    short8v kfr[4], qfr[2];
#pragma unroll
    for (int i = 0; i < 4; ++i)
      kfr[i] = *(const short8v*)&ksm[h * 2560 + (i * 16 + l15) * 40 + lhi * 8];
#pragma unroll
    for (int j = 0; j < 2; ++j)
      qfr[j] = *(const short8v*)&qsm[h * 2560 + (g * 32 + j * 16 + l15) * 40 + lhi * 8];

    // all waves hold q/k fragments in registers; psm may now overwrite q+k
    __syncthreads();

    const float* maskw = mask + (b & 63) * (49 * 49);

#pragma unroll
    for (int j = 0; j < 2; ++j) {
      const f32x4 zero = {0.f, 0.f, 0.f, 0.f};
      f32x4 s[4];
#pragma unroll
      for (int i = 0; i < 4; ++i) s[i] = mfma16(kfr[i], qfr[j], zero);

      const int qq = g * 32 + j * 16 + l15;      // query column held by this lane
      const unsigned qi = (unsigned)qq / 7u;
      const unsigned qjj = (unsigned)qq - qi * 7u;
      float lg[4][4];
#pragma unroll
      for (int i = 0; i < 4; ++i) {
#pragma unroll
        for (int r = 0; r < 4; ++r) {
          const int key = i * 16 + lhi * 4 + r;
          float v = s[i][r];
          if (qq < 49 && key < 49) {
            const unsigned ki = (unsigned)key / 7u;
            const unsigned kj = (unsigned)key - ki * 7u;
            const int idx = (int)((qi - ki + 6u) * 13u + (qjj - kj + 6u));
            v += bias_table[idx * 4 + h] + maskw[qq * 49 + key];
          }
          if (key >= 49) v = -1e30f;
          lg[i][r] = v;
        }
      }
      float mx = lg[0][0];
#pragma unroll
      for (int i = 0; i < 4; ++i)
#pragma unroll
        for (int r = 0; r < 4; ++r) mx = fmaxf(mx, lg[i][r]);
      mx = fmaxf(mx, __shfl_xor(mx, 16));
      mx = fmaxf(mx, __shfl_xor(mx, 32));
      float sum = 0.f;
#pragma unroll
      for (int i = 0; i < 4; ++i)
#pragma unroll
        for (int r = 0; r < 4; ++r) { lg[i][r] = __expf(lg[i][r] - mx); sum += lg[i][r]; }
      sum += __shfl_xor(sum, 16);
      sum += __shfl_xor(sum, 32);
      const float inv = 1.f / sum;
#pragma unroll
      for (int i = 0; i < 4; ++i) {
        short4v p;
#pragma unroll
        for (int r = 0; r < 4; ++r) p[r] = f2bf(lg[i][r] * inv);
        *(short4v*)&psm[h * 4608 + qq * 72 + i * 16 + lhi * 4] = p;
      }
    }

    // ---- PV: out[q][d] = sum_k P[q][k] * V[k][d]
    f32x4 oacc[2][2];
    const f32x4 zero = {0.f, 0.f, 0.f, 0.f};
#pragma unroll
    for (int mt = 0; mt < 2; ++mt)
#pragma unroll
      for (int nt = 0; nt < 2; ++nt) oacc[mt][nt] = zero;
#pragma unroll
    for (int ks = 0; ks < 2; ++ks) {
      short8v pf[2], vf[2];
#pragma unroll
      for (int mt = 0; mt < 2; ++mt)
        pf[mt] = *(const short8v*)&psm[h * 4608 + (g * 32 + mt * 16 + l15) * 72 + ks * 32 + lhi * 8];
#pragma unroll
      for (int nt = 0; nt < 2; ++nt)
        vf[nt] = *(const short8v*)&vtm[h * 2304 + (nt * 16 + l15) * 72 + ks * 32 + lhi * 8];
#pragma unroll
      for (int mt = 0; mt < 2; ++mt)
#pragma unroll
        for (int nt = 0; nt < 2; ++nt) oacc[mt][nt] = mfma16(pf[mt], vf[nt], oacc[mt][nt]);
    }
#pragma unroll
    for (int mt = 0; mt < 2; ++mt)
#pragma unroll
      for (int nt = 0; nt < 2; ++nt)
#pragma unroll
        for (int r = 0; r < 4; ++r)
          aom[(g * 32 + mt * 16 + lhi * 4 + r) * 136 + h * 32 + nt * 16 + l15] =
              f2bf(oacc[mt][nt][r]);
  }
  __syncthreads();

  // ---- Phase 3: output projection Y = AO @ proj_w^T + proj_b
  {
    short8v afr[2][4];
#pragma unroll
    for (int mt = 0; mt < 2; ++mt)
#pragma unroll
      for (int ks = 0; ks < 4; ++ks)
        afr[mt][ks] = *(const short8v*)&aom[(g * 32 + mt * 16 + l15) * 136 + ks * 32 + lhi * 8];

    float* outw = out + (long)b * (WS_TOK * DIMC);
#pragma unroll
    for (int nt = 0; nt < 2; ++nt) {
      const int ncol = h * 32 + nt * 16 + l15;
      short8v wfr[4];
#pragma unroll
      for (int ks = 0; ks < 4; ++ks)
        wfr[ks] = *(const short8v*)&wp[ncol * 128 + ks * 32 + lhi * 8];
      const float pb = proj_b[ncol];
      f32x4 a0 = {pb, pb, pb, pb};
      f32x4 a1 = a0;
#pragma unroll
      for (int ks = 0; ks < 4; ++ks) {
        a0 = mfma16(afr[0][ks], wfr[ks], a0);
        a1 = mfma16(afr[1][ks], wfr[ks], a1);
      }
#pragma unroll
      for (int r = 0; r < 4; ++r) {
        const int m0 = g * 32 + lhi * 4 + r;
        if (m0 < 49) outw[m0 * 128 + ncol] = a0[r];
        const int m1 = m0 + 16;
        if (m1 < 49) outw[m1 * 128 + ncol] = a1[r];
      }
    }
  }
}

extern "C" void kernel_launch(void* const* d_in, const int* in_sizes, int n_in,
                              void* d_out, int out_size, void* d_ws, size_t ws_size,
                              hipStream_t stream) {
  const float* x          = (const float*)d_in[0];
  const float* mask       = (const float*)d_in[1];
  const float* qkv_w      = (const float*)d_in[2];
  const float* qkv_b      = (const float*)d_in[3];
  const float* proj_w     = (const float*)d_in[4];
  const float* proj_b     = (const float*)d_in[5];
  const float* bias_table = (const float*)d_in[6];

  short* wq = (short*)d_ws;        // 384*128 bf16
  short* wp = wq + 49152;          // 128*128 bf16

  cvt_weights_kernel<<<dim3(192), dim3(256), 0, stream>>>(qkv_w, proj_w, wq, wp);
  win_attn_kernel<<<dim3(4096), dim3(512), 0, stream>>>(
      x, mask, qkv_b, proj_b, bias_table, wq, wp, (float*)d_out);
}

// Round 3
// 180.263 us; speedup vs baseline: 1.4028x; 1.1711x over previous
//
#include <hip/hip_runtime.h>
#include <stdint.h>

typedef float  f32x4   __attribute__((ext_vector_type(4)));
typedef float  float4v __attribute__((ext_vector_type(4)));
typedef short  short4v __attribute__((ext_vector_type(4)));
typedef short  short8v __attribute__((ext_vector_type(8)));
typedef __bf16 bf16x8  __attribute__((ext_vector_type(8)));

static __device__ __forceinline__ short f2bf(float f) {
  unsigned u = __builtin_bit_cast(unsigned, f);
  u += 0x7FFFu + ((u >> 16) & 1u);
  return (short)(u >> 16);
}

static __device__ __forceinline__ f32x4 mfma16(short8v a, short8v b, f32x4 c) {
  return __builtin_amdgcn_mfma_f32_16x16x32_bf16(
      __builtin_bit_cast(bf16x8, a), __builtin_bit_cast(bf16x8, b), c, 0, 0, 0);
}

static __device__ __forceinline__ short8v cat44(short4v a, short4v b) {
  short8v r;
  r[0] = a[0]; r[1] = a[1]; r[2] = a[2]; r[3] = a[3];
  r[4] = b[0]; r[5] = b[1]; r[6] = b[2]; r[7] = b[3];
  return r;
}

// Prelude A: convert qkv_w (384x128) and proj_w (128x128) f32 -> bf16.
__global__ void cvt_weights_kernel(const float* __restrict__ qkv_w,
                                   const float* __restrict__ proj_w,
                                   short* __restrict__ wq, short* __restrict__ wp) {
  int i = blockIdx.x * 256 + threadIdx.x;   // grid = 192 blocks -> 49152
  wq[i] = f2bf(qkv_w[i]);
  if (i < 16384) wp[i] = f2bf(proj_w[i]);
}

// Prelude B: combined bias+mask table laid out as the MFMA S-fragment:
// cmb[w(64)][h(4)][qt(4)][i(4)][lane(64)][r(4)] f32  (4 MB)
// key = i*16 + (lane>>4)*4 + r ; q = qt*16 + (lane&15)
__global__ void build_cmb_kernel(const float* __restrict__ mask,
                                 const float* __restrict__ bias_table,
                                 float* __restrict__ cmb) {
  int id   = blockIdx.x * 256 + threadIdx.x;   // grid = 1024 blocks -> 262144
  int lane = id & 63;
  int i    = (id >> 6) & 3;
  int qt   = (id >> 8) & 3;
  int h    = (id >> 10) & 3;
  int w    = id >> 12;
  int q     = qt * 16 + (lane & 15);
  int kbase = i * 16 + ((lane >> 4) << 2);
  f32x4 v;
#pragma unroll
  for (int r = 0; r < 4; ++r) {
    int key = kbase + r;
    float val;
    if (key >= 49) {
      val = -1e30f;
    } else if (q >= 49) {
      val = 0.f;
    } else {
      int qi = q / 7, qj = q - qi * 7;
      int ki = key / 7, kj = key - ki * 7;
      int ridx = (qi - ki + 6) * 13 + (qj - kj + 6);
      val = bias_table[ridx * 4 + h] + mask[w * 2401 + q * 49 + key];
    }
    v[r] = val;
  }
  ((f32x4*)cmb)[id] = v;
}

// One block = one window (49 tokens padded to 64). 512 threads = 8 waves.
// wave (g,h): g = token half (32 rows), h = head.
// LDS 52 KiB -> 3 blocks/CU at VGPR<=85:
//   [0,8704)      xb  [64][136] bf16 x   -> later aom [64][136]
//   [8704,17920)  ksm [4][64][36] k (d-major per key row)
//   [17920,26624) vtm [4][32][68] v^T: row = h*32+d, col = token
__global__ __launch_bounds__(512, 6)
void win_attn_kernel(const float* __restrict__ x,
                     const float* __restrict__ qkv_b,
                     const float* __restrict__ proj_b,
                     const short* __restrict__ wq,
                     const short* __restrict__ wp,
                     const float* __restrict__ cmb,
                     float* __restrict__ out) {
  __shared__ __align__(16) short smem[26624];
  short* xb  = smem;
  short* ksm = smem + 8704;
  short* vtm = smem + 17920;
  short* aom = smem;     // alias over xb

  const int b    = blockIdx.x;
  const int tid  = threadIdx.x;
  const int lane = tid & 63;
  const int wv   = tid >> 6;
  const int h    = wv & 3;
  const int g    = wv >> 2;
  const int l15  = lane & 15;
  const int lhi  = lane >> 4;

  // ---- Phase 0: stage x -> bf16 LDS, zero pad rows 49..63
  {
    short4v z = {0, 0, 0, 0};
    for (int idx = tid; idx < 510; idx += 512)
      *(short4v*)&xb[49 * 136 + idx * 4] = z;
    const float* xw = x + (long)b * (49 * 128);
    for (int idx = tid; idx < 1568; idx += 512) {
      int m  = idx >> 5;
      int c0 = (idx & 31) << 2;
      float4v v = *(const float4v*)&xw[m * 128 + c0];
      short4v s;
      s[0] = f2bf(v[0]); s[1] = f2bf(v[1]); s[2] = f2bf(v[2]); s[3] = f2bf(v[3]);
      *(short4v*)&xb[m * 136 + c0] = s;
    }
  }
  __syncthreads();

  // ---- Phase 1: QKV projection. Q,K swapped (acc = [ncol][token]); V normal.
  short8v qfr[2];
  {
    short8v afr[2][4];
#pragma unroll
    for (int mt = 0; mt < 2; ++mt)
#pragma unroll
      for (int ks = 0; ks < 4; ++ks)
        afr[mt][ks] = *(const short8v*)&xb[(g * 32 + mt * 16 + l15) * 136 + ks * 32 + lhi * 8];

    const float scale = 0.1767766952966369f;  // 32^-0.5

#pragma unroll
    for (int mat = 0; mat < 2; ++mat) {     // 0 = Q, 1 = K (swapped orientation)
      f32x4 acc[2][2];                       // [jt][nt]
#pragma unroll
      for (int nt = 0; nt < 2; ++nt) {
        const int wrow = mat * 128 + h * 32 + nt * 16;
        short8v bfr[4];
#pragma unroll
        for (int ks = 0; ks < 4; ++ks)
          bfr[ks] = *(const short8v*)&wq[(wrow + l15) * 128 + ks * 32 + lhi * 8];
        const f32x4 bias4 = *(const f32x4*)&qkv_b[wrow + lhi * 4];
#pragma unroll
        for (int jt = 0; jt < 2; ++jt) {
          acc[jt][nt] = bias4;
#pragma unroll
          for (int ks = 0; ks < 4; ++ks)
            acc[jt][nt] = mfma16(bfr[ks], afr[jt][ks], acc[jt][nt]);
        }
      }
      if (mat == 0) {
#pragma unroll
        for (int jt = 0; jt < 2; ++jt) {
          short8v qv;
#pragma unroll
          for (int nt = 0; nt < 2; ++nt)
#pragma unroll
            for (int r = 0; r < 4; ++r)
              qv[nt * 4 + r] = f2bf(acc[jt][nt][r] * scale);
          qfr[jt] = qv;
        }
      } else {
#pragma unroll
        for (int jt = 0; jt < 2; ++jt)
#pragma unroll
          for (int nt = 0; nt < 2; ++nt)
#pragma unroll
            for (int r = 0; r < 4; ++r)
              ksm[h * 2304 + (g * 32 + jt * 16 + l15) * 36 + nt * 16 + lhi * 4 + r] =
                  f2bf(acc[jt][nt][r]);
      }
    }

    // V (normal orientation): acc = [token][dcol], store transposed short4
#pragma unroll
    for (int nt = 0; nt < 2; ++nt) {
      const int wrow = 256 + h * 32 + nt * 16;
      short8v bfr[4];
#pragma unroll
      for (int ks = 0; ks < 4; ++ks)
        bfr[ks] = *(const short8v*)&wq[(wrow + l15) * 128 + ks * 32 + lhi * 8];
      const float vb = qkv_b[wrow + l15];
#pragma unroll
      for (int mt = 0; mt < 2; ++mt) {
        f32x4 acc = {vb, vb, vb, vb};
#pragma unroll
        for (int ks = 0; ks < 4; ++ks)
          acc = mfma16(afr[mt][ks], bfr[ks], acc);
        short4v p;
#pragma unroll
        for (int r = 0; r < 4; ++r) p[r] = f2bf(acc[r]);
        *(short4v*)&vtm[(h * 32 + nt * 16 + l15) * 68 + g * 32 + mt * 16 + lhi * 4] = p;
      }
    }
  }
  __syncthreads();

  // ---- Phase 2: S = mfma(K,Q) + cmb; softmax in-lane; swapped PV from regs
  {
    short8v kfr[4];
#pragma unroll
    for (int i = 0; i < 4; ++i) {
      const int ka = h * 2304 + (i * 16 + l15) * 36 + lhi * 4;
      kfr[i] = cat44(*(const short4v*)&ksm[ka], *(const short4v*)&ksm[ka + 16]);
    }
    const f32x4* cmb4 = (const f32x4*)cmb;
    const long cbase = (long)(b & 63) * 4096 + h * 1024 + g * 512 + lane;

#pragma unroll
    for (int jt = 0; jt < 2; ++jt) {
      f32x4 s[4];
#pragma unroll
      for (int i = 0; i < 4; ++i)
        s[i] = mfma16(kfr[i], qfr[jt], cmb4[cbase + jt * 256 + i * 64]);

      float mx = s[0][0];
#pragma unroll
      for (int i = 0; i < 4; ++i)
#pragma unroll
        for (int r = 0; r < 4; ++r) mx = fmaxf(mx, s[i][r]);
      mx = fmaxf(mx, __shfl_xor(mx, 16));
      mx = fmaxf(mx, __shfl_xor(mx, 32));
      float sum = 0.f;
#pragma unroll
      for (int i = 0; i < 4; ++i)
#pragma unroll
        for (int r = 0; r < 4; ++r) {
          float e = __expf(s[i][r] - mx);
          s[i][r] = e;
          sum += e;
        }
      sum += __shfl_xor(sum, 16);
      sum += __shfl_xor(sum, 32);
      const float inv = 1.f / sum;

      short8v pb[2];
#pragma unroll
      for (int ks = 0; ks < 2; ++ks) {
        short8v pv;
#pragma unroll
        for (int e = 0; e < 4; ++e) pv[e]     = f2bf(s[2 * ks][e] * inv);
#pragma unroll
        for (int e = 0; e < 4; ++e) pv[4 + e] = f2bf(s[2 * ks + 1][e] * inv);
        pb[ks] = pv;
      }

#pragma unroll
      for (int dt = 0; dt < 2; ++dt) {
        f32x4 o = {0.f, 0.f, 0.f, 0.f};
#pragma unroll
        for (int ks = 0; ks < 2; ++ks) {
          const int va = (h * 32 + dt * 16 + l15) * 68 + ks * 32 + lhi * 4;
          short8v vfr = cat44(*(const short4v*)&vtm[va], *(const short4v*)&vtm[va + 16]);
          o = mfma16(vfr, pb[ks], o);
        }
        short4v p;
#pragma unroll
        for (int r = 0; r < 4; ++r) p[r] = f2bf(o[r]);
        *(short4v*)&aom[(g * 32 + jt * 16 + l15) * 136 + h * 32 + dt * 16 + lhi * 4] = p;
      }
    }
  }
  __syncthreads();

  // ---- Phase 3: output projection Y = AO @ proj_w^T + proj_b
  {
    short8v pfr[2][4];
#pragma unroll
    for (int mt = 0; mt < 2; ++mt)
#pragma unroll
      for (int ks = 0; ks < 4; ++ks)
        pfr[mt][ks] = *(const short8v*)&aom[(g * 32 + mt * 16 + l15) * 136 + ks * 32 + lhi * 8];

    float* outw = out + (long)b * (49 * 128);
#pragma unroll
    for (int nt = 0; nt < 2; ++nt) {
      const int ncol = h * 32 + nt * 16 + l15;
      short8v wfr[4];
#pragma unroll
      for (int ks = 0; ks < 4; ++ks)
        wfr[ks] = *(const short8v*)&wp[ncol * 128 + ks * 32 + lhi * 8];
      const float pbv = proj_b[ncol];
      f32x4 a0 = {pbv, pbv, pbv, pbv};
      f32x4 a1 = a0;
#pragma unroll
      for (int ks = 0; ks < 4; ++ks) {
        a0 = mfma16(pfr[0][ks], wfr[ks], a0);
        a1 = mfma16(pfr[1][ks], wfr[ks], a1);
      }
#pragma unroll
      for (int r = 0; r < 4; ++r) {
        const int m0 = g * 32 + lhi * 4 + r;
        if (m0 < 49) outw[m0 * 128 + ncol] = a0[r];
        const int m1 = m0 + 16;
        if (m1 < 49) outw[m1 * 128 + ncol] = a1[r];
      }
    }
  }
}

extern "C" void kernel_launch(void* const* d_in, const int* in_sizes, int n_in,
                              void* d_out, int out_size, void* d_ws, size_t ws_size,
                              hipStream_t stream) {
  const float* x          = (const float*)d_in[0];
  const float* mask       = (const float*)d_in[1];
  const float* qkv_w      = (const float*)d_in[2];
  const float* qkv_b      = (const float*)d_in[3];
  const float* proj_w     = (const float*)d_in[4];
  const float* proj_b     = (const float*)d_in[5];
  const float* bias_table = (const float*)d_in[6];

  short* wq  = (short*)d_ws;                         // 384*128 bf16 (98304 B)
  short* wp  = wq + 49152;                           // 128*128 bf16 (32768 B)
  float* cmb = (float*)((char*)d_ws + 131072);       // 4 MB combined bias+mask

  cvt_weights_kernel<<<dim3(192), dim3(256), 0, stream>>>(qkv_w, proj_w, wq, wp);
  build_cmb_kernel<<<dim3(1024), dim3(256), 0, stream>>>(mask, bias_table, cmb);
  win_attn_kernel<<<dim3(4096), dim3(512), 0, stream>>>(
      x, qkv_b, proj_b, wq, wp, cmb, (float*)d_out);
}

// Round 4
// 157.769 us; speedup vs baseline: 1.6029x; 1.1426x over previous
//
#include <hip/hip_runtime.h>
#include <stdint.h>

typedef float  f32x4   __attribute__((ext_vector_type(4)));
typedef float  float4v __attribute__((ext_vector_type(4)));
typedef short  short4v __attribute__((ext_vector_type(4)));
typedef short  short8v __attribute__((ext_vector_type(8)));
typedef __bf16 bf16x8  __attribute__((ext_vector_type(8)));

static __device__ __forceinline__ short f2bf(float f) {
  unsigned u = __builtin_bit_cast(unsigned, f);
  u += 0x7FFFu + ((u >> 16) & 1u);
  return (short)(u >> 16);
}

static __device__ __forceinline__ f32x4 mfma16(short8v a, short8v b, f32x4 c) {
  return __builtin_amdgcn_mfma_f32_16x16x32_bf16(
      __builtin_bit_cast(bf16x8, a), __builtin_bit_cast(bf16x8, b), c, 0, 0, 0);
}

static __device__ __forceinline__ short8v cat44(short4v a, short4v b) {
  short8v r;
  r[0] = a[0]; r[1] = a[1]; r[2] = a[2]; r[3] = a[3];
  r[4] = b[0]; r[5] = b[1]; r[6] = b[2]; r[7] = b[3];
  return r;
}

// Prelude A: convert qkv_w (384x128) and proj_w (128x128) f32 -> bf16.
__global__ void cvt_weights_kernel(const float* __restrict__ qkv_w,
                                   const float* __restrict__ proj_w,
                                   short* __restrict__ wq, short* __restrict__ wp) {
  int i = blockIdx.x * 256 + threadIdx.x;   // grid = 192 blocks -> 49152
  wq[i] = f2bf(qkv_w[i]);
  if (i < 16384) wp[i] = f2bf(proj_w[i]);
}

// Prelude B: combined bias+mask table laid out as the MFMA S-fragment:
// cmb[w(64)][h(4)][qt(4)][i(4)][lane(64)][r(4)] f32  (4 MB)
// key = i*16 + (lane>>4)*4 + r ; q = qt*16 + (lane&15)
__global__ void build_cmb_kernel(const float* __restrict__ mask,
                                 const float* __restrict__ bias_table,
                                 float* __restrict__ cmb) {
  int id   = blockIdx.x * 256 + threadIdx.x;   // grid = 1024 blocks -> 262144
  int lane = id & 63;
  int i    = (id >> 6) & 3;
  int qt   = (id >> 8) & 3;
  int h    = (id >> 10) & 3;
  int w    = id >> 12;
  int q     = qt * 16 + (lane & 15);
  int kbase = i * 16 + ((lane >> 4) << 2);
  f32x4 v;
#pragma unroll
  for (int r = 0; r < 4; ++r) {
    int key = kbase + r;
    float val;
    if (key >= 49) {
      val = -1e30f;
    } else if (q >= 49) {
      val = 0.f;
    } else {
      int qi = q / 7, qj = q - qi * 7;
      int ki = key / 7, kj = key - ki * 7;
      int ridx = (qi - ki + 6) * 13 + (qj - kj + 6);
      val = bias_table[ridx * 4 + h] + mask[w * 2401 + q * 49 + key];
    }
    v[r] = val;
  }
  ((f32x4*)cmb)[id] = v;
}

// One block = one window (49 tokens padded to 64). 512 threads = 8 waves.
// wave (g,h): g = token half (32 rows), h = head.
// LDS 52 KiB -> 3 blocks/CU; ks-outer loops keep VGPR < ~85 (no spills).
//   [0,8704)      xb  [64][136] bf16 x   -> later aom [64][136]
//   [8704,17920)  ksm [4][64][36] k (d-major per key row)
//   [17920,26624) vtm [4][32][68] v^T: row = h*32+d, col = token
__global__ __launch_bounds__(512, 5)
void win_attn_kernel(const float* __restrict__ x,
                     const float* __restrict__ qkv_b,
                     const float* __restrict__ proj_b,
                     const short* __restrict__ wq,
                     const short* __restrict__ wp,
                     const float* __restrict__ cmb,
                     float* __restrict__ out) {
  __shared__ __align__(16) short smem[26624];
  short* xb  = smem;
  short* ksm = smem + 8704;
  short* vtm = smem + 17920;
  short* aom = smem;     // alias over xb

  const int b    = blockIdx.x;
  const int tid  = threadIdx.x;
  const int lane = tid & 63;
  const int wv   = tid >> 6;
  const int h    = wv & 3;
  const int g    = wv >> 2;
  const int l15  = lane & 15;
  const int lhi  = lane >> 4;

  // ---- Phase 0: stage x -> bf16 LDS, zero pad rows 49..63
  {
    short4v z = {0, 0, 0, 0};
    for (int idx = tid; idx < 510; idx += 512)
      *(short4v*)&xb[49 * 136 + idx * 4] = z;
    const float* xw = x + (long)b * (49 * 128);
    for (int idx = tid; idx < 1568; idx += 512) {
      int m  = idx >> 5;
      int c0 = (idx & 31) << 2;
      float4v v = *(const float4v*)&xw[m * 128 + c0];
      short4v s;
      s[0] = f2bf(v[0]); s[1] = f2bf(v[1]); s[2] = f2bf(v[2]); s[3] = f2bf(v[3]);
      *(short4v*)&xb[m * 136 + c0] = s;
    }
  }
  __syncthreads();

  // ---- Phase 1a: Q,K projection, swapped (acc rows = w-col, cols = token).
  // ks-outer so A-fragments die each iteration (register pressure control).
  short8v qfr[2];
  {
    f32x4 qk[2][2][2];   // [mat][nt][jt]
#pragma unroll
    for (int mat = 0; mat < 2; ++mat)
#pragma unroll
      for (int nt = 0; nt < 2; ++nt) {
        const f32x4 bias4 = *(const f32x4*)&qkv_b[mat * 128 + h * 32 + nt * 16 + lhi * 4];
        qk[mat][nt][0] = bias4;
        qk[mat][nt][1] = bias4;
      }
#pragma unroll
    for (int ks = 0; ks < 4; ++ks) {
      const short8v a0 = *(const short8v*)&xb[(g * 32 + l15) * 136 + ks * 32 + lhi * 8];
      const short8v a1 = *(const short8v*)&xb[(g * 32 + 16 + l15) * 136 + ks * 32 + lhi * 8];
#pragma unroll
      for (int mat = 0; mat < 2; ++mat)
#pragma unroll
        for (int nt = 0; nt < 2; ++nt) {
          const short8v bfr =
              *(const short8v*)&wq[(mat * 128 + h * 32 + nt * 16 + l15) * 128 + ks * 32 + lhi * 8];
          qk[mat][nt][0] = mfma16(bfr, a0, qk[mat][nt][0]);
          qk[mat][nt][1] = mfma16(bfr, a1, qk[mat][nt][1]);
        }
    }
    const float scale = 0.1767766952966369f;  // 32^-0.5
#pragma unroll
    for (int jt = 0; jt < 2; ++jt) {
      short8v qv;
#pragma unroll
      for (int nt = 0; nt < 2; ++nt)
#pragma unroll
        for (int r = 0; r < 4; ++r)
          qv[nt * 4 + r] = f2bf(qk[0][nt][jt][r] * scale);
      qfr[jt] = qv;
    }
#pragma unroll
    for (int jt = 0; jt < 2; ++jt)
#pragma unroll
      for (int nt = 0; nt < 2; ++nt)
#pragma unroll
        for (int r = 0; r < 4; ++r)
          ksm[h * 2304 + (g * 32 + jt * 16 + l15) * 36 + nt * 16 + lhi * 4 + r] =
              f2bf(qk[1][nt][jt][r]);
  }

  // ---- Phase 1b: V projection (normal orientation), store transposed.
  {
    f32x4 av[2][2];      // [nt][mt]
#pragma unroll
    for (int nt = 0; nt < 2; ++nt) {
      const float vb = qkv_b[256 + h * 32 + nt * 16 + l15];
      av[nt][0] = f32x4{vb, vb, vb, vb};
      av[nt][1] = av[nt][0];
    }
#pragma unroll
    for (int ks = 0; ks < 4; ++ks) {
      const short8v a0 = *(const short8v*)&xb[(g * 32 + l15) * 136 + ks * 32 + lhi * 8];
      const short8v a1 = *(const short8v*)&xb[(g * 32 + 16 + l15) * 136 + ks * 32 + lhi * 8];
#pragma unroll
      for (int nt = 0; nt < 2; ++nt) {
        const short8v bfr =
            *(const short8v*)&wq[(256 + h * 32 + nt * 16 + l15) * 128 + ks * 32 + lhi * 8];
        av[nt][0] = mfma16(a0, bfr, av[nt][0]);
        av[nt][1] = mfma16(a1, bfr, av[nt][1]);
      }
    }
#pragma unroll
    for (int nt = 0; nt < 2; ++nt)
#pragma unroll
      for (int mt = 0; mt < 2; ++mt) {
        short4v p;
#pragma unroll
        for (int r = 0; r < 4; ++r) p[r] = f2bf(av[nt][mt][r]);
        *(short4v*)&vtm[(h * 32 + nt * 16 + l15) * 68 + g * 32 + mt * 16 + lhi * 4] = p;
      }
  }
  __syncthreads();

  // ---- Phase 2: S = mfma(K,Q) + cmb; softmax in-lane; swapped PV from regs
  {
    short8v kfr[4];
#pragma unroll
    for (int i = 0; i < 4; ++i) {
      const int ka = h * 2304 + (i * 16 + l15) * 36 + lhi * 4;
      kfr[i] = cat44(*(const short4v*)&ksm[ka], *(const short4v*)&ksm[ka + 16]);
    }
    const f32x4* cmb4 = (const f32x4*)cmb;
    const long cbase = (long)(b & 63) * 4096 + h * 1024 + g * 512 + lane;

#pragma unroll
    for (int jt = 0; jt < 2; ++jt) {
      f32x4 s[4];
#pragma unroll
      for (int i = 0; i < 4; ++i)
        s[i] = mfma16(kfr[i], qfr[jt], cmb4[cbase + jt * 256 + i * 64]);

      float mx = s[0][0];
#pragma unroll
      for (int i = 0; i < 4; ++i)
#pragma unroll
        for (int r = 0; r < 4; ++r) mx = fmaxf(mx, s[i][r]);
      mx = fmaxf(mx, __shfl_xor(mx, 16));
      mx = fmaxf(mx, __shfl_xor(mx, 32));
      float sum = 0.f;
#pragma unroll
      for (int i = 0; i < 4; ++i)
#pragma unroll
        for (int r = 0; r < 4; ++r) {
          float e = __expf(s[i][r] - mx);
          s[i][r] = e;
          sum += e;
        }
      sum += __shfl_xor(sum, 16);
      sum += __shfl_xor(sum, 32);
      const float inv = 1.f / sum;

      short8v pb[2];
#pragma unroll
      for (int ks = 0; ks < 2; ++ks) {
        short8v pv;
#pragma unroll
        for (int e = 0; e < 4; ++e) pv[e]     = f2bf(s[2 * ks][e] * inv);
#pragma unroll
        for (int e = 0; e < 4; ++e) pv[4 + e] = f2bf(s[2 * ks + 1][e] * inv);
        pb[ks] = pv;
      }

#pragma unroll
      for (int dt = 0; dt < 2; ++dt) {
        f32x4 o = {0.f, 0.f, 0.f, 0.f};
#pragma unroll
        for (int ks = 0; ks < 2; ++ks) {
          const int va = (h * 32 + dt * 16 + l15) * 68 + ks * 32 + lhi * 4;
          short8v vfr = cat44(*(const short4v*)&vtm[va], *(const short4v*)&vtm[va + 16]);
          o = mfma16(vfr, pb[ks], o);
        }
        short4v p;
#pragma unroll
        for (int r = 0; r < 4; ++r) p[r] = f2bf(o[r]);
        *(short4v*)&aom[(g * 32 + jt * 16 + l15) * 136 + h * 32 + dt * 16 + lhi * 4] = p;
      }
    }
  }
  __syncthreads();

  // ---- Phase 3: output projection Y = AO @ proj_w^T + proj_b (ks-outer)
  {
    f32x4 po[2][2];      // [nt][mt]
#pragma unroll
    for (int nt = 0; nt < 2; ++nt) {
      const float pbv = proj_b[h * 32 + nt * 16 + l15];
      po[nt][0] = f32x4{pbv, pbv, pbv, pbv};
      po[nt][1] = po[nt][0];
    }
#pragma unroll
    for (int ks = 0; ks < 4; ++ks) {
      const short8v p0 = *(const short8v*)&aom[(g * 32 + l15) * 136 + ks * 32 + lhi * 8];
      const short8v p1 = *(const short8v*)&aom[(g * 32 + 16 + l15) * 136 + ks * 32 + lhi * 8];
#pragma unroll
      for (int nt = 0; nt < 2; ++nt) {
        const short8v wfr =
            *(const short8v*)&wp[(h * 32 + nt * 16 + l15) * 128 + ks * 32 + lhi * 8];
        po[nt][0] = mfma16(p0, wfr, po[nt][0]);
        po[nt][1] = mfma16(p1, wfr, po[nt][1]);
      }
    }
    float* outw = out + (long)b * (49 * 128);
#pragma unroll
    for (int nt = 0; nt < 2; ++nt) {
      const int ncol = h * 32 + nt * 16 + l15;
#pragma unroll
      for (int r = 0; r < 4; ++r) {
        const int m0 = g * 32 + lhi * 4 + r;
        if (m0 < 49) outw[m0 * 128 + ncol] = po[nt][0][r];
        const int m1 = m0 + 16;
        if (m1 < 49) outw[m1 * 128 + ncol] = po[nt][1][r];
      }
    }
  }
}

extern "C" void kernel_launch(void* const* d_in, const int* in_sizes, int n_in,
                              void* d_out, int out_size, void* d_ws, size_t ws_size,
                              hipStream_t stream) {
  const float* x          = (const float*)d_in[0];
  const float* mask       = (const float*)d_in[1];
  const float* qkv_w      = (const float*)d_in[2];
  const float* qkv_b      = (const float*)d_in[3];
  const float* proj_w     = (const float*)d_in[4];
  const float* proj_b     = (const float*)d_in[5];
  const float* bias_table = (const float*)d_in[6];

  short* wq  = (short*)d_ws;                         // 384*128 bf16 (98304 B)
  short* wp  = wq + 49152;                           // 128*128 bf16 (32768 B)
  float* cmb = (float*)((char*)d_ws + 131072);       // 4 MB combined bias+mask

  cvt_weights_kernel<<<dim3(192), dim3(256), 0, stream>>>(qkv_w, proj_w, wq, wp);
  build_cmb_kernel<<<dim3(1024), dim3(256), 0, stream>>>(mask, bias_table, cmb);
  win_attn_kernel<<<dim3(4096), dim3(512), 0, stream>>>(
      x, qkv_b, proj_b, wq, wp, cmb, (float*)d_out);
}